// Round 8
// baseline (201.151 us; speedup 1.0000x reference)
//
#include <hip/hip_runtime.h>

#define NEG_INF_F (-1e30f)
#define MARGIN_F 0.1f
#define TABN 4096
#define BR 256     // rows per block
#define NT 512     // threads per block (8 waves)
#define LDK 261    // kt leading dim: 261%32=5 -> b128 reads conflict-free, writes 2-way

// ---- monotone float<->uint key for LDS atomicMax on floats ----
__device__ __forceinline__ unsigned fkey(float f) {
    unsigned b = __float_as_uint(f);
    return (b & 0x80000000u) ? ~b : (b | 0x80000000u);
}
__device__ __forceinline__ float fdec(unsigned k) {
    unsigned b = (k & 0x80000000u) ? (k ^ 0x80000000u) : ~k;
    return __uint_as_float(b);
}

// ============================================================
// Kernel A: setup (1 block). id->bitmask tables, gathered qT,
// zero barrier words.
// ============================================================
__global__ __launch_bounds__(256) void setup_kernel(
    const float* __restrict__ inputs_col,
    const int* __restrict__ targets_col,
    const int* __restrict__ qidxs,
    const int* __restrict__ pidxs,
    const int* __restrict__ nnegs,
    unsigned* __restrict__ ptab,    // [TABN]
    unsigned* __restrict__ ntab,    // [TABN]
    float* __restrict__ qT,         // [128][32] k-major
    unsigned* __restrict__ bar,     // [96]: cnt@0, flag@32, ticket@64
    int d, int Q, int P, int Nn, int triplet_len)
{
    __shared__ int qmap[32];
    const int tid = threadIdx.x;

    if (tid < Q) {
        int t = targets_col[tid * triplet_len];
        int l = 0;
        for (int i = Q - 1; i >= 0; --i) if (qidxs[i] == t) l = i;  // argmax semantics
        qmap[tid] = l;
    }
    for (int i = tid; i < TABN; i += 256) { ptab[i] = 0u; ntab[i] = 0u; }
    if (tid < 96) bar[tid] = 0u;
    __syncthreads();

    for (int i = tid; i < Q * P; i += 256) {
        int q = i / P, k = i - q * P;
        int id = pidxs[qmap[q] * P + k];
        if ((unsigned)id < TABN) atomicOr(&ptab[id], 1u << q);
    }
    for (int i = tid; i < Q * Nn; i += 256) {
        int q = i / Nn, k = i - q * Nn;
        int id = nnegs[qmap[q] * Nn + k];
        if ((unsigned)id < TABN) atomicOr(&ntab[id], 1u << q);
    }
    for (int i = tid; i < d * Q; i += 256) {
        int dd = i >> 5, q = i & 31;    // Q == 32
        qT[i] = inputs_col[(size_t)(q * triplet_len) * d + dd];
    }
}

// ============================================================
// Sense-reversing grid barrier: arrivals add to cnt (no reader
// contention); spinners poll a different cacheline written once.
// Residency: 256 blocks = 256 CUs, >=1 block/CU capacity.
// ============================================================
__device__ __forceinline__ void gsync(unsigned* cnt, unsigned* flag, unsigned nblk) {
    __syncthreads();
    if (threadIdx.x == 0) {
        __threadfence();
        unsigned old = atomicAdd(cnt, 1u);
        if (old == nblk - 1u) {
            __hip_atomic_store(flag, 1u, __ATOMIC_RELEASE, __HIP_MEMORY_SCOPE_AGENT);
        } else {
            while (__hip_atomic_load(flag, __ATOMIC_RELAXED, __HIP_MEMORY_SCOPE_AGENT) == 0u)
                __builtin_amdgcn_s_sleep(8);
        }
        __threadfence();
    }
    __syncthreads();
}

// ============================================================
// Fused kernel: 256 blocks x 512 thr. 4 chunks of BK=32.
// Staging: 100%-coalesced (128B/row), MLP=4, issued AFTER the
// buf-ready barrier so latency hides under the chunk's compute.
// Inner loop: 2x ds_read_b128 per 16 FMA (conflict-free).
// ============================================================
__global__ __launch_bounds__(NT, 1) void fused_kernel(
    const float* __restrict__ qT,        // [128][32]
    const float* __restrict__ rows,      // [m][128]
    const int* __restrict__ targets_row,
    const unsigned* __restrict__ ptab,
    const unsigned* __restrict__ ntab,
    float* __restrict__ gmax,            // [64][nb]
    float* __restrict__ psum,            // [nb][160]
    unsigned* __restrict__ bar,          // [96]
    float* __restrict__ out,
    int m, int nb)
{
    __shared__ float qv[128][32];        // 16 KB, [k][q]
    __shared__ float kt[32][LDK];        // 33.4 KB, [k][row]
    __shared__ unsigned pbm[BR], nbm[BR];
    __shared__ unsigned spk[32], snk[32];
    __shared__ float sthr[2][32];
    __shared__ float wpart[8][32][5];
    __shared__ float fin[160];
    __shared__ int islast;

    const int tid  = threadIdx.x;
    const int bid  = blockIdx.x;
    const int j0   = bid * BR;
    const int lane = tid & 63;
    const int wave = tid >> 6;           // 0..7
    const int qg   = lane & 7, q0 = qg * 4;
    const int rgl  = lane >> 3;          // 0..7
    const int rloc = wave * 32 + rgl * 4;

    // stage qv (flat float4 copy; same [k][q] layout)
    for (int i = tid; i < 128 * 32 / 4; i += NT)
        ((float4*)qv)[i] = ((const float4*)qT)[i];
    if (tid < 32) { spk[tid] = fkey(NEG_INF_F); snk[tid] = fkey(NEG_INF_F); }
    if (tid < BR) {
        int j = j0 + tid;
        unsigned pbv = 0u, nbv = 0u;
        if (j < m) {
            int t = targets_row[j];
            if ((unsigned)t < TABN) { pbv = ptab[t]; nbv = ~ntab[t]; }
            else                    { nbv = ~0u; }
        }
        pbm[tid] = pbv; nbm[tid] = nbv;
    }

    // staging ids: thread -> rows srow+64p (p=0..3), 16B slot kk
    const int srow = tid >> 3;           // 0..63
    const int kk   = tid & 7;            // 0..7
    const float* gbase = rows + (size_t)(j0 + srow) * 128 + kk * 4;

    float4 vA[4], vB[4];

#define LOADV(V, C) { _Pragma("unroll") \
    for (int p = 0; p < 4; ++p) \
        V[p] = *(const float4*)(gbase + (size_t)(64 * p) * 128 + (C) * 32); }

#define WRITEV(V) { _Pragma("unroll") \
    for (int p = 0; p < 4; ++p) { \
        kt[kk * 4 + 0][srow + 64 * p] = V[p].x; \
        kt[kk * 4 + 1][srow + 64 * p] = V[p].y; \
        kt[kk * 4 + 2][srow + 64 * p] = V[p].z; \
        kt[kk * 4 + 3][srow + 64 * p] = V[p].w; } }

#define COMPUTE(C) { _Pragma("unroll") \
    for (int k = 0; k < 32; ++k) { \
        float4 qf = *(const float4*)&qv[(C) * 32 + k][q0]; \
        float4 rf = *(const float4*)&kt[k][rloc]; \
        const float* qp = (const float*)&qf; \
        const float* rp = (const float*)&rf; \
        _Pragma("unroll") \
        for (int qi = 0; qi < 4; ++qi) \
            _Pragma("unroll") \
            for (int ri = 0; ri < 4; ++ri) \
                acc[qi][ri] = fmaf(qp[qi], rp[ri], acc[qi][ri]); } }

    float acc[4][4];
#pragma unroll
    for (int a = 0; a < 4; ++a)
#pragma unroll
        for (int b = 0; b < 4; ++b) acc[a][b] = 0.f;

    LOADV(vA, 0)
    // chunk 0
    __syncthreads();                 // qv/pbm ready; vA drained (needed now)
    WRITEV(vA)
    __syncthreads();                 // kt ready
    LOADV(vB, 1)                     // in flight during compute(0)
    COMPUTE(0)
    // chunk 1
    __syncthreads();                 // readers done; vB drained (arrived long ago)
    WRITEV(vB)
    __syncthreads();
    LOADV(vA, 2)
    COMPUTE(1)
    // chunk 2
    __syncthreads();
    WRITEV(vA)
    __syncthreads();
    LOADV(vB, 3)
    COMPUTE(2)
    // chunk 3
    __syncthreads();
    WRITEV(vB)
    __syncthreads();
    COMPUTE(3)

    unsigned pb[4], nbr[4];
#pragma unroll
    for (int r = 0; r < 4; ++r) { pb[r] = pbm[rloc + r]; nbr[r] = nbm[rloc + r]; }

    // block masked maxes -> LDS atomics -> plain stores to gmax
#pragma unroll
    for (int qi = 0; qi < 4; ++qi) {
        const int q = q0 + qi;
        float pmax = NEG_INF_F, nmax = NEG_INF_F;
#pragma unroll
        for (int r = 0; r < 4; ++r) {
            if ((pb[r] >> q) & 1u)  pmax = fmaxf(pmax, acc[qi][r]);
            if ((nbr[r] >> q) & 1u) nmax = fmaxf(nmax, acc[qi][r]);
        }
#pragma unroll
        for (int off = 32; off >= 8; off >>= 1) {
            pmax = fmaxf(pmax, __shfl_down(pmax, off));
            nmax = fmaxf(nmax, __shfl_down(nmax, off));
        }
        if (lane < 8) {
            atomicMax(&spk[q], fkey(pmax));
            atomicMax(&snk[q], fkey(nmax));
        }
    }
    __syncthreads();
    if (tid < 64) {
        int side = tid >> 5, q = tid & 31;
        gmax[(size_t)tid * nb + bid] = fdec(side ? snk[q] : spk[q]);
    }

    gsync(&bar[0], &bar[32], (unsigned)nb);

    // ---- phase 2: thresholds from gmax scan ----
    {
        int p = tid >> 3, c = tid & 7;   // 64 pairs x 8 scanners
        float mv = NEG_INF_F;
        for (int b = c; b < nb; b += 8) mv = fmaxf(mv, gmax[(size_t)p * nb + b]);
#pragma unroll
        for (int msk = 1; msk <= 4; msk <<= 1) mv = fmaxf(mv, __shfl_xor(mv, msk));
        if (c == 0) sthr[p >> 5][p & 31] = mv;
    }
    __syncthreads();

    // selection on register acc -> block partials
#pragma unroll
    for (int qi = 0; qi < 4; ++qi) {
        const int q = q0 + qi;
        const float posThr = sthr[1][q] + MARGIN_F;               // s < neg_max + margin
        const float negThr = fmaxf(0.4f, sthr[0][q]) - MARGIN_F;  // s > max(0.4,pos_max) - margin
        float ps = 0.f, pc = 0.f, ns = 0.f, nc = 0.f, pmc = 0.f;
#pragma unroll
        for (int r = 0; r < 4; ++r) {
            float s = acc[qi][r];
            unsigned pm = (pb[r] >> q) & 1u;
            unsigned nm = (nbr[r] >> q) & 1u;
            pmc += (float)pm;
            if (pm && s < posThr) { ps += 1.f - s; pc += 1.f; }
            if (nm && s > negThr) { ns += s;       nc += 1.f; }
        }
#pragma unroll
        for (int off = 32; off >= 8; off >>= 1) {
            ps  += __shfl_down(ps, off);
            pc  += __shfl_down(pc, off);
            ns  += __shfl_down(ns, off);
            nc  += __shfl_down(nc, off);
            pmc += __shfl_down(pmc, off);
        }
        if (lane < 8) {
            wpart[wave][lane * 4 + qi][0] = ps;
            wpart[wave][lane * 4 + qi][1] = pc;
            wpart[wave][lane * 4 + qi][2] = ns;
            wpart[wave][lane * 4 + qi][3] = nc;
            wpart[wave][lane * 4 + qi][4] = pmc;
        }
    }
    __syncthreads();
    if (tid < 160) {
        float v = 0.f;
#pragma unroll
        for (int w = 0; w < 8; ++w) v += wpart[w][tid / 5][tid % 5];
        psum[(size_t)bid * 160 + tid] = v;   // plain store
    }

    // ---- ticket + last-block finalize ----
    __syncthreads();
    if (tid == 0) {
        __threadfence();
        unsigned old = atomicAdd(&bar[64], 1u);
        islast = (old == (unsigned)(nb - 1)) ? 1 : 0;
    }
    __syncthreads();
    if (islast) {
        if (tid == 0) __threadfence();
        __syncthreads();
        if (tid < 160) {
            float v = 0.f;
            for (int b = 0; b < nb; ++b) v += psum[(size_t)b * 160 + tid];
            fin[tid] = v;
        }
        __syncthreads();
        if (tid < 64) {
            float v = 0.f;
            if (tid < 32) {
                float psv = fin[tid * 5 + 0];
                float pcv = fin[tid * 5 + 1];
                float nsv = fin[tid * 5 + 2];
                float ncv = fin[tid * 5 + 3];
                float pmc = fin[tid * 5 + 4];
                float pl = (pcv > 0.f) ? psv / pcv : 0.f;
                float nl = (ncv > 0.f) ? nsv / ncv : 0.f;
                v = (pmc > 0.f) ? (pl + nl) : 0.f;
            }
#pragma unroll
            for (int off = 32; off; off >>= 1) v += __shfl_down(v, off);
            if (tid == 0) out[0] = v / 32.0f;
        }
    }
}

// ============================================================
extern "C" void kernel_launch(void* const* d_in, const int* in_sizes, int n_in,
                              void* d_out, int out_size, void* d_ws, size_t ws_size,
                              hipStream_t stream)
{
    const float* inputs_col = (const float*)d_in[0];
    const float* inputs_row = (const float*)d_in[1];
    const int* targets_col  = (const int*)d_in[2];
    const int* targets_row  = (const int*)d_in[3];
    const int* qidxs        = (const int*)d_in[4];
    const int* pidxs        = (const int*)d_in[5];
    const int* nnegs        = (const int*)d_in[6];

    const int n  = in_sizes[2];
    int m        = in_sizes[3];
    const int Q  = in_sizes[4];            // 32
    const int P  = in_sizes[5] / Q;        // 10
    const int Nn = in_sizes[6] / Q;        // 25
    const int d  = in_sizes[0] / n;        // 128
    const int triplet_len = n / Q;         // 12

    int nb = (m + BR - 1) / BR;            // 256

    char* ws = (char*)d_ws;
    size_t off = 0;
    unsigned* ptab = (unsigned*)(ws + off); off += (size_t)TABN * 4;
    unsigned* ntab = (unsigned*)(ws + off); off += (size_t)TABN * 4;
    float* qT      = (float*)(ws + off);    off += (size_t)d * Q * 4;
    unsigned* bar  = (unsigned*)(ws + off); off += 96 * 4;
    float* gmax    = (float*)(ws + off);    off += (size_t)64 * nb * 4;
    float* psum    = (float*)(ws + off);    off += (size_t)nb * 160 * 4;
    float* out     = (float*)d_out;

    setup_kernel<<<1, 256, 0, stream>>>(inputs_col, targets_col, qidxs, pidxs, nnegs,
                                        ptab, ntab, qT, bar,
                                        d, Q, P, Nn, triplet_len);

    fused_kernel<<<nb, NT, 0, stream>>>(qT, inputs_row, targets_row, ptab, ntab,
                                        gmax, psum, bar, out, m, nb);
}